// Round 4
// baseline (938.992 us; speedup 1.0000x reference)
//
#include <hip/hip_runtime.h>

// ============================================================================
// PromptViT fused pipeline, f32 throughout (exactness vs reference; no fp32
// MFMA on CDNA4 anyway). Key structural choices:
//  - sim = (pn . keys_row) * rsqrt(|keys_row|^2): norm fused into the GEMM
//    pass so keys is read ONCE.
//  - sim <= 1 (cosine) => softmax without max-shift: Z[b] = sum_masked exp(s).
//  - Fast path (device flag): if no batch row has entropy <= 2.0 then wv==0
//    identically => keys_new==keys, prompts_new==prompt_vals BITWISE. The
//    sim pass and the retrieved pass fuse those copies (saves ~350MB of
//    re-reads); general-path kernels kE/kF handle any other input and
//    early-exit here.
// ============================================================================

#define THR_C   0.005f
#define THR_ENT 2.0f
#define ALPHA_C 0.1f

constexpr int BB = 64;
constexpr int CC = 1000;
constexpr int NN = 50000;
constexpr int DD = 768;

// d_out layout (floats)
constexpr size_t OUT_KEYS = (size_t)BB * DD;              // 49152
constexpr size_t OUT_PROM = OUT_KEYS + (size_t)NN * CC;   // 50,049,152

// ws layout (floats)
constexpr size_t OFF_PN    = 0;
constexpr size_t OFF_PROBS = OFF_PN + (size_t)BB * CC;
constexpr size_t OFF_ENTOK = OFF_PROBS + (size_t)BB * CC;
constexpr size_t OFF_FLAG  = OFF_ENTOK + 64;              // 1.0 => fast path
constexpr size_t OFF_MATCH = OFF_FLAG + 64;
constexpr size_t OFF_ZINV  = OFF_MATCH + 64;
constexpr size_t OFF_VALID = OFF_ZINV + 64;
constexpr size_t OFF_PC1   = OFF_VALID + 64;
constexpr size_t OFF_PZ1   = OFF_PC1 + 256 * 64;
constexpr size_t OFF_SIM   = OFF_PZ1 + 256 * 64;          // [NN][64]
constexpr size_t OFF_PD    = OFF_SIM + (size_t)NN * 64;

// ---------------------------------------------------------------------------
// kA: per-row softmax stats from logits: probs, pn (L2-normalized probs),
// entropy flag. 64 blocks (one per b).
// ---------------------------------------------------------------------------
__global__ __launch_bounds__(256) void kA(const float* __restrict__ logits,
                                          float* __restrict__ ws) {
  __shared__ float red[256];
  const int b = blockIdx.x, t = threadIdx.x;
  float z[4]; bool vld[4];
  #pragma unroll
  for (int k = 0; k < 4; ++k) {
    int i = t + 256 * k; vld[k] = (i < CC);
    z[k] = vld[k] ? logits[b * CC + i] : -3.4e38f;
  }
  float lm = fmaxf(fmaxf(z[0], z[1]), fmaxf(z[2], z[3]));
  red[t] = lm; __syncthreads();
  for (int s = 128; s > 0; s >>= 1) { if (t < s) red[t] = fmaxf(red[t], red[t + s]); __syncthreads(); }
  const float M = red[0]; __syncthreads();

  float e[4], ls = 0.f;
  #pragma unroll
  for (int k = 0; k < 4; ++k) { e[k] = vld[k] ? __expf(z[k] - M) : 0.f; ls += e[k]; }
  red[t] = ls; __syncthreads();
  for (int s = 128; s > 0; s >>= 1) { if (t < s) red[t] += red[t + s]; __syncthreads(); }
  const float S = red[0]; __syncthreads();

  float lzw = 0.f;
  #pragma unroll
  for (int k = 0; k < 4; ++k) lzw += e[k] * (vld[k] ? (z[k] - M) : 0.f);
  red[t] = lzw; __syncthreads();
  for (int s = 128; s > 0; s >>= 1) { if (t < s) red[t] += red[t + s]; __syncthreads(); }
  const float ZW = red[0]; __syncthreads();

  const float Sinv = 1.f / S;
  float p[4], lp2 = 0.f;
  #pragma unroll
  for (int k = 0; k < 4; ++k) { p[k] = e[k] * Sinv; lp2 += p[k] * p[k]; }
  red[t] = lp2; __syncthreads();
  for (int s = 128; s > 0; s >>= 1) { if (t < s) red[t] += red[t + s]; __syncthreads(); }
  const float rn = rsqrtf(red[0]);

  #pragma unroll
  for (int k = 0; k < 4; ++k) if (vld[k]) {
    int i = t + 256 * k;
    ws[OFF_PROBS + b * CC + i] = p[k];
    ws[OFF_PN + b * CC + i] = p[k] * rn;
  }
  if (t == 0) {
    float ent = logf(S) - ZW * Sinv;   // -sum p log p
    ws[OFF_ENTOK + b] = (ent <= THR_ENT) ? 1.f : 0.f;
  }
}

// kC0: fast-path flag = (no row with ent<=THR). 1 block, 64 threads (1 wave).
__global__ void kC0(float* __restrict__ ws) {
  const int t = threadIdx.x;
  unsigned long long m = __ballot(ws[OFF_ENTOK + t] > 0.5f);
  if (t == 0) ws[OFF_FLAG] = (m == 0ull) ? 1.f : 0.f;
}

// ---------------------------------------------------------------------------
// kB: sim GEMM. Tile: 128 n x 64 b, K=1000 in 25 chunks of 40.
// Per thread: 8b x 4n accumulators. Register prefetch of the next K-chunk
// overlaps global latency with FMA. Row sumsq accumulated via LDS atomics =>
// sim = dot * rsqrt(nsq). Fast path: streams keys tile back out as keys_new
// (bitwise copy).
// ---------------------------------------------------------------------------
constexpr int B_NT = 128;
constexpr int B_KC = 40;
static_assert(CC % B_KC == 0, "K chunking");

__global__ __launch_bounds__(256) void kB(const float* __restrict__ keys,
                                          float* __restrict__ ws,
                                          float* __restrict__ keys_new) {
  __shared__ float kT[B_KC][132];   // [k][n] transposed, stride 132
  __shared__ float pT[B_KC][68];    // [k][b] transposed, stride 68
  __shared__ float nsq[B_NT];
  __shared__ float sflag;
  const int t = threadIdx.x;
  const int n0 = blockIdx.x * B_NT;
  if (t == 0) sflag = ws[OFF_FLAG];
  if (t < B_NT) nsq[t] = 0.f;

  float4 kreg[5]; float preg[10];
  const float* __restrict__ pnb = ws + OFF_PN;

  auto loadChunk = [&](int k0) {
    #pragma unroll
    for (int i = 0; i < 5; ++i) {
      int idx = t + 256 * i; int row = idx / 10, c4 = idx - row * 10;
      int n = n0 + row;
      kreg[i] = (n < NN) ? *(const float4*)(keys + (size_t)n * CC + k0 + c4 * 4)
                         : make_float4(0.f, 0.f, 0.f, 0.f);
    }
    #pragma unroll
    for (int i = 0; i < 10; ++i) {
      int idx = t + 256 * i; int bb = idx / 40, c = idx - bb * 40;
      preg[i] = pnb[bb * CC + k0 + c];
    }
  };
  loadChunk(0);

  float acc[8][4];
  #pragma unroll
  for (int i = 0; i < 8; ++i)
    #pragma unroll
    for (int j = 0; j < 4; ++j) acc[i][j] = 0.f;

  const int bg = t >> 5, ng = t & 31;

  for (int ch = 0; ch < CC / B_KC; ++ch) {
    __syncthreads();                     // prev compute done; sflag/nsq visible
    const bool fast = (sflag > 0.5f);
    const int k0 = ch * B_KC;
    // ---- write phase: regs -> LDS (transposed), sumsq, fused keys_new copy
    #pragma unroll
    for (int i = 0; i < 5; ++i) {
      int idx = t + 256 * i; int row = idx / 10, c4 = idx - row * 10;
      float4 v = kreg[i];
      kT[c4 * 4 + 0][row] = v.x; kT[c4 * 4 + 1][row] = v.y;
      kT[c4 * 4 + 2][row] = v.z; kT[c4 * 4 + 3][row] = v.w;
      int n = n0 + row;
      if (n < NN) {
        atomicAdd(&nsq[row], v.x * v.x + v.y * v.y + v.z * v.z + v.w * v.w);
        if (fast) *(float4*)(keys_new + (size_t)n * CC + k0 + c4 * 4) = v;
      }
    }
    #pragma unroll
    for (int i = 0; i < 10; ++i) {
      int idx = t + 256 * i; int bb = idx / 40, c = idx - bb * 40;
      pT[c][bb] = preg[i];
    }
    __syncthreads();
    if (ch + 1 < CC / B_KC) loadChunk(k0 + B_KC);   // prefetch next chunk
    // ---- compute phase
    #pragma unroll 8
    for (int k = 0; k < B_KC; ++k) {
      const float4 kv = *(const float4*)(&kT[k][ng * 4]);
      const float4 pa = *(const float4*)(&pT[k][bg * 8]);
      const float4 pb = *(const float4*)(&pT[k][bg * 8 + 4]);
      const float pvs[8] = {pa.x, pa.y, pa.z, pa.w, pb.x, pb.y, pb.z, pb.w};
      const float kvs[4] = {kv.x, kv.y, kv.z, kv.w};
      #pragma unroll
      for (int ii = 0; ii < 8; ++ii)
        #pragma unroll
        for (int jj = 0; jj < 4; ++jj)
          acc[ii][jj] = fmaf(pvs[ii], kvs[jj], acc[ii][jj]);
    }
  }
  __syncthreads();
  // epilogue: sim[n][b] = acc * rsqrt(|keys_n|^2)
  #pragma unroll
  for (int jj = 0; jj < 4; ++jj) {
    const int nl = ng * 4 + jj, n = n0 + nl;
    if (n < NN) {
      const float rn = rsqrtf(nsq[nl]);
      float* o = ws + OFF_SIM + (size_t)n * 64 + bg * 8;
      *(float4*)(o)     = make_float4(acc[0][jj] * rn, acc[1][jj] * rn, acc[2][jj] * rn, acc[3][jj] * rn);
      *(float4*)(o + 4) = make_float4(acc[4][jj] * rn, acc[5][jj] * rn, acc[6][jj] * rn, acc[7][jj] * rn);
    }
  }
}

// kC1: per-block partial masked-count and sum(exp(sim)) per b. 256 blocks.
__global__ __launch_bounds__(256) void kC1(float* __restrict__ ws) {
  __shared__ float redc[256], redz[256];
  const int t = threadIdx.x, b = t & 63, g = t >> 6;
  float cnt = 0.f, zz = 0.f;
  for (int base = blockIdx.x * 4; base < NN; base += 1024) {
    int n = base + g;
    if (n < NN) {
      float s = ws[OFF_SIM + (size_t)n * 64 + b];
      if (s > THR_C) { cnt += 1.f; zz += __expf(s); }
    }
  }
  redc[t] = cnt; redz[t] = zz; __syncthreads();
  if (t < 64) {
    cnt = redc[t] + redc[t + 64] + redc[t + 128] + redc[t + 192];
    zz  = redz[t] + redz[t + 64] + redz[t + 128] + redz[t + 192];
    ws[OFF_PC1 + blockIdx.x * 64 + t] = cnt;
    ws[OFF_PZ1 + blockIdx.x * 64 + t] = zz;
  }
}

// kC2: finalize matched / Zinv / valid. 1 block.
__global__ __launch_bounds__(256) void kC2(float* __restrict__ ws) {
  __shared__ float redc[256], redz[256];
  const int t = threadIdx.x, b = t & 63, g = t >> 6;
  float cnt = 0.f, zz = 0.f;
  for (int blk = g; blk < 256; blk += 4) {
    cnt += ws[OFF_PC1 + blk * 64 + b];
    zz  += ws[OFF_PZ1 + blk * 64 + b];
  }
  redc[t] = cnt; redz[t] = zz; __syncthreads();
  if (t < 64) {
    cnt = redc[t] + redc[t + 64] + redc[t + 128] + redc[t + 192];
    zz  = redz[t] + redz[t + 64] + redz[t + 128] + redz[t + 192];
    const float matched = (cnt > 0.f) ? 1.f : 0.f;
    ws[OFF_MATCH + t] = matched;
    ws[OFF_ZINV + t] = (cnt > 0.f) ? 1.f / zz : 0.f;
    ws[OFF_VALID + t] = (matched > 0.5f && ws[OFF_ENTOK + t] > 0.5f) ? 1.f : 0.f;
  }
}

// ---------------------------------------------------------------------------
// kD: retrieved partial GEMM: C[64b][256d] += w[b][n] * pv[n][d] over an
// n-slice. w recomputed from sim on the fly (exp * Zinv). Fast path fuses the
// prompts_new = pv copy (spread across waves via bg==(j&7)).
// ---------------------------------------------------------------------------
__global__ __launch_bounds__(256) void kD(const float* __restrict__ pv,
                                          float* __restrict__ ws,
                                          float* __restrict__ prompts_out,
                                          int nch, int npc) {
  __shared__ float wl[16][64];
  __shared__ float zl[64];
  __shared__ float sfl;
  const int t = threadIdx.x;
  if (t < 64) zl[t] = ws[OFF_ZINV + t];
  if (t == 0) sfl = ws[OFF_FLAG];
  const int dc = blockIdx.x, nc = blockIdx.y;
  const int d0 = dc * 256;
  const int nstart = nc * npc;
  const int nend = min(nstart + npc, NN);
  const int bg = t >> 5, dg = t & 31;
  float acc[8][8];
  #pragma unroll
  for (int i = 0; i < 8; ++i)
    #pragma unroll
    for (int j = 0; j < 8; ++j) acc[i][j] = 0.f;
  __syncthreads();
  const bool fast = (sfl > 0.5f);

  auto body = [&](int nb, int j) {
    const int n = nb + j;
    const float* pp = pv + (size_t)n * DD + d0 + dg * 8;
    const float4 a = *(const float4*)(pp);
    const float4 c = *(const float4*)(pp + 4);
    if (fast && bg == (j & 7)) {
      float* po = prompts_out + (size_t)n * DD + d0 + dg * 8;
      *(float4*)(po) = a; *(float4*)(po + 4) = c;
    }
    const float4 wA = *(const float4*)(&wl[j][bg * 8]);
    const float4 wB = *(const float4*)(&wl[j][bg * 8 + 4]);
    const float wss[8] = {wA.x, wA.y, wA.z, wA.w, wB.x, wB.y, wB.z, wB.w};
    const float ps[8] = {a.x, a.y, a.z, a.w, c.x, c.y, c.z, c.w};
    #pragma unroll
    for (int ii = 0; ii < 8; ++ii)
      #pragma unroll
      for (int jj = 0; jj < 8; ++jj)
        acc[ii][jj] = fmaf(wss[ii], ps[jj], acc[ii][jj]);
  };

  for (int nb = nstart; nb < nend; nb += 16) {
    {  // stage w for 16 n
      const int nl = t >> 4, b4 = (t & 15) * 4;
      const int n = nb + nl;
      float4 wv = make_float4(0.f, 0.f, 0.f, 0.f);
      if (n < nend) {
        const float4 s = *(const float4*)(ws + OFF_SIM + (size_t)n * 64 + b4);
        wv.x = (s.x > THR_C) ? __expf(s.x) * zl[b4 + 0] : 0.f;
        wv.y = (s.y > THR_C) ? __expf(s.y) * zl[b4 + 1] : 0.f;
        wv.z = (s.z > THR_C) ? __expf(s.z) * zl[b4 + 2] : 0.f;
        wv.w = (s.w > THR_C) ? __expf(s.w) * zl[b4 + 3] : 0.f;
      }
      *(float4*)(&wl[nl][b4]) = wv;
    }
    __syncthreads();
    const int nlim = min(16, nend - nb);
    if (nlim == 16) {
      #pragma unroll 4
      for (int j = 0; j < 16; ++j) body(nb, j);
    } else {
      for (int j = 0; j < nlim; ++j) body(nb, j);
    }
    __syncthreads();
  }
  float* pb = ws + OFF_PD + ((size_t)(dc * nch + nc)) * 16384;
  #pragma unroll
  for (int ii = 0; ii < 8; ++ii) {
    const int b = bg * 8 + ii;
    *(float4*)(pb + b * 256 + dg * 8)     = make_float4(acc[ii][0], acc[ii][1], acc[ii][2], acc[ii][3]);
    *(float4*)(pb + b * 256 + dg * 8 + 4) = make_float4(acc[ii][4], acc[ii][5], acc[ii][6], acc[ii][7]);
  }
}

// kD2: reduce partials -> retrieved, substitute init_prompt when !matched.
__global__ __launch_bounds__(256) void kD2(const float* __restrict__ ws,
                                           const float* __restrict__ initp,
                                           float* __restrict__ retr_out, int nch) {
  const int gid = blockIdx.x * 256 + threadIdx.x;   // < 64*768
  const int b = gid / DD, d = gid - b * DD;
  const int dc = d >> 8, dl = d & 255;
  float s = 0.f;
  for (int k = 0; k < nch; ++k)
    s += ws[OFF_PD + ((size_t)(dc * nch + k)) * 16384 + b * 256 + dl];
  if (ws[OFF_MATCH + b] < 0.5f) s = initp[d];
  retr_out[gid] = s;
}

// kE: general keys_new (exclusive-suffix-product form). Early-exits on fast
// path (kB already wrote the bitwise copy).
__global__ __launch_bounds__(256) void kE(const float* __restrict__ keys,
                                          const float* __restrict__ ws,
                                          float* __restrict__ keys_new) {
  if (ws[OFF_FLAG] > 0.5f) return;
  __shared__ float zl[64], vl[64];
  const int t = threadIdx.x;
  if (t < 64) { zl[t] = ws[OFF_ZINV + t]; vl[t] = ws[OFF_VALID + t]; }
  __syncthreads();
  const int stride = gridDim.x * 256;
  for (int idx = blockIdx.x * 256 + t; idx < NN * CC; idx += stride) {
    const int n = idx / CC, c = idx - n * CC;
    float S = 1.f, av = 0.f;
    for (int b = 63; b >= 0; --b) {
      const float s = ws[OFF_SIM + (size_t)n * 64 + b];
      const float w = (s > THR_C) ? __expf(s) * zl[b] : 0.f;
      const float wv = w * vl[b];
      av = fmaf(ALPHA_C * wv * S, ws[OFF_PROBS + b * CC + c], av);
      S *= 1.f - ALPHA_C * wv;
    }
    keys_new[idx] = keys[idx] * S + av;
  }
}

// kF: general prompts_new. Early-exits on fast path (kD wrote the copy).
__global__ __launch_bounds__(256) void kF(const float* __restrict__ pv,
                                          const float* __restrict__ ws,
                                          const float* __restrict__ retr,
                                          float* __restrict__ prompts_new) {
  if (ws[OFF_FLAG] > 0.5f) return;
  __shared__ float zl[64], vl[64];
  const int t = threadIdx.x;
  if (t < 64) { zl[t] = ws[OFF_ZINV + t]; vl[t] = ws[OFF_VALID + t]; }
  __syncthreads();
  const int stride = gridDim.x * 256;
  for (int idx = blockIdx.x * 256 + t; idx < NN * DD; idx += stride) {
    const int n = idx / DD, d = idx - n * DD;
    float S = 1.f, av = 0.f;
    for (int b = 63; b >= 0; --b) {
      const float s = ws[OFF_SIM + (size_t)n * 64 + b];
      const float w = (s > THR_C) ? __expf(s) * zl[b] : 0.f;
      const float wv = w * vl[b];
      av = fmaf(wv * S, retr[b * DD + d], av);
      S *= 1.f - wv;
    }
    prompts_new[idx] = pv[idx] * S + av;
  }
}

extern "C" void kernel_launch(void* const* d_in, const int* in_sizes, int n_in,
                              void* d_out, int out_size, void* d_ws, size_t ws_size,
                              hipStream_t stream) {
  const float* logits = (const float*)d_in[0];
  const float* keys   = (const float*)d_in[1];
  const float* pv     = (const float*)d_in[2];
  const float* initp  = (const float*)d_in[3];
  float* out = (float*)d_out;
  float* ws  = (float*)d_ws;
  float* retr_out    = out;
  float* keys_out    = out + OUT_KEYS;
  float* prompts_out = out + OUT_PROM;

  // pass-D n-chunking: default 85 (grid 3x85=255 blocks ~ 1/CU), shrink if
  // workspace is tight. ws must at least hold sim + one partial set.
  const size_t ws_floats = ws_size / sizeof(float);
  int nch = 85;
  if (OFF_PD + (size_t)3 * nch * 16384 > ws_floats) {
    long avail = (long)ws_floats - (long)OFF_PD;
    long fit = avail / (3 * 16384);
    nch = (int)((fit < 1) ? 1 : (fit > 85 ? 85 : fit));
  }
  const int npc = (NN + nch - 1) / nch;

  hipLaunchKernelGGL(kA,  dim3(64),  dim3(256), 0, stream, logits, ws);
  hipLaunchKernelGGL(kC0, dim3(1),   dim3(64),  0, stream, ws);
  hipLaunchKernelGGL(kB,  dim3((NN + B_NT - 1) / B_NT), dim3(256), 0, stream, keys, ws, keys_out);
  hipLaunchKernelGGL(kC1, dim3(256), dim3(256), 0, stream, ws);
  hipLaunchKernelGGL(kC2, dim3(1),   dim3(256), 0, stream, ws);
  hipLaunchKernelGGL(kD,  dim3(3, nch), dim3(256), 0, stream, pv, ws, prompts_out, nch, npc);
  hipLaunchKernelGGL(kD2, dim3((BB * DD) / 256), dim3(256), 0, stream, ws, initp, retr_out, nch);
  hipLaunchKernelGGL(kE,  dim3(1024), dim3(256), 0, stream, keys, ws, keys_out);
  hipLaunchKernelGGL(kF,  dim3(1024), dim3(256), 0, stream, pv, ws, retr_out, prompts_out);
}